// Round 1
// baseline (112.080 us; speedup 1.0000x reference)
//
#include <hip/hip_runtime.h>
#include <hip/hip_bf16.h>

// ---------------------------------------------------------------------------
// BlockedMLP: out = (relu(bsr(relu(x@W1^T+b1))+b2)) @ W3^T + b3
// B=2048, IN=1024, H=2048, OUT=1024, BS=32, RB=CB=64, K=32 blocks/row
// Strategy: convert f32 inputs -> bf16 in ws, then 3 MFMA layers (bf16 in,
// f32 accum). Threshold is 2% of absmax -> bf16 compute passes comfortably.
// ---------------------------------------------------------------------------

typedef __attribute__((ext_vector_type(8))) short bf16x8;
typedef __attribute__((ext_vector_type(4))) float f32x4;

__device__ __forceinline__ unsigned short f2bf(float f) {
    union { float f; unsigned int u; } c; c.f = f;
    unsigned int u = c.u;
    u += 0x7fffu + ((u >> 16) & 1u);   // round-to-nearest-even
    return (unsigned short)(u >> 16);
}

__device__ __forceinline__ void async16(const void* g, void* l) {
    __builtin_amdgcn_global_load_lds(
        (const __attribute__((address_space(1))) void*)g,
        (__attribute__((address_space(3))) void*)l,
        16, 0, 0);
}

// ---------------------------------------------------------------------------
// f32 -> bf16 conversion, 4 elems/thread
// ---------------------------------------------------------------------------
__global__ __launch_bounds__(256) void cvt_f32_bf16(
    const float* __restrict__ in, unsigned short* __restrict__ out, int n)
{
    int i = (blockIdx.x * 256 + threadIdx.x) * 4;
    if (i + 3 < n) {
        float4 v = *reinterpret_cast<const float4*>(in + i);
        ushort4 o;
        o.x = f2bf(v.x); o.y = f2bf(v.y); o.z = f2bf(v.z); o.w = f2bf(v.w);
        *reinterpret_cast<ushort4*>(out + i) = o;
    } else {
        for (; i < n; ++i) out[i] = f2bf(in[i]);
    }
}

// ---------------------------------------------------------------------------
// bf16 GEMM, B^T form: C[M,N] = A[M,K] x B[N,K]^T + bias, optional relu.
// 128x128 tile, BK=32, 256 threads = 4 waves (2x2), each wave 64x64 = 4x4
// frags of mfma_f32_16x16x32_bf16. global_load_lds width-16 staging.
// M,N multiples of 128; K multiple of 32.
// ---------------------------------------------------------------------------
template<int RELU, int OUT_BF16>
__global__ __launch_bounds__(256) void gemm_bt(
    const unsigned short* __restrict__ A,
    const unsigned short* __restrict__ B,
    const float* __restrict__ bias,
    void* __restrict__ Cout,
    int M, int N, int K)
{
    __shared__ unsigned short As[128 * 32];
    __shared__ unsigned short Bs[128 * 32];
    const int t = threadIdx.x;
    const int w = t >> 6;
    const int l = t & 63;
    const int bm = blockIdx.x * 128;
    const int bn = blockIdx.y * 128;
    const int wm = (w >> 1) * 64;
    const int wn = (w & 1) * 64;

    f32x4 acc[4][4];
    #pragma unroll
    for (int i = 0; i < 4; ++i)
        #pragma unroll
        for (int j = 0; j < 4; ++j)
            acc[i][j] = (f32x4){0.f, 0.f, 0.f, 0.f};

    // staging: linear load idx = t (+256); row = idx/4, 8-elem chunk = idx%4
    const int rr = t >> 2;
    const int cc = (t & 3) * 8;
    const unsigned short* gA0 = A + (size_t)(bm + rr) * K + cc;
    const unsigned short* gA1 = A + (size_t)(bm + 64 + rr) * K + cc;
    const unsigned short* gB0 = B + (size_t)(bn + rr) * K + cc;
    const unsigned short* gB1 = B + (size_t)(bn + 64 + rr) * K + cc;
    unsigned short* lA0 = As + w * 512;          // wave-uniform LDS bases
    unsigned short* lA1 = As + 2048 + w * 512;
    unsigned short* lB0 = Bs + w * 512;
    unsigned short* lB1 = Bs + 2048 + w * 512;

    const int fr = l & 15;       // fragment row/col
    const int kg = l >> 4;       // k-group: k = kg*8 + i
    const int nK = K >> 5;
    for (int kt = 0; kt < nK; ++kt) {
        async16(gA0, lA0);
        async16(gA1, lA1);
        async16(gB0, lB0);
        async16(gB1, lB1);
        gA0 += 32; gA1 += 32; gB0 += 32; gB1 += 32;
        __syncthreads();   // compiler drains vmcnt before s_barrier

        bf16x8 af[4], bg[4];
        #pragma unroll
        for (int i = 0; i < 4; ++i)
            af[i] = *reinterpret_cast<const bf16x8*>(&As[(wm + i * 16 + fr) * 32 + kg * 8]);
        #pragma unroll
        for (int j = 0; j < 4; ++j)
            bg[j] = *reinterpret_cast<const bf16x8*>(&Bs[(wn + j * 16 + fr) * 32 + kg * 8]);
        #pragma unroll
        for (int i = 0; i < 4; ++i)
            #pragma unroll
            for (int j = 0; j < 4; ++j)
                acc[i][j] = __builtin_amdgcn_mfma_f32_16x16x32_bf16(af[i], bg[j], acc[i][j], 0, 0, 0);
        __syncthreads();
    }

    // epilogue: C/D layout col = l&15, row = (l>>4)*4 + v  [m89/m91 verified]
    const int fq = l >> 4;
    #pragma unroll
    for (int i = 0; i < 4; ++i) {
        const int row0 = bm + wm + i * 16 + fq * 4;
        #pragma unroll
        for (int j = 0; j < 4; ++j) {
            const int col = bn + wn + j * 16 + fr;
            const float bv = bias[col];
            #pragma unroll
            for (int v = 0; v < 4; ++v) {
                float r = acc[i][j][v] + bv;
                if (RELU) r = fmaxf(r, 0.f);
                const size_t off = (size_t)(row0 + v) * N + col;
                if (OUT_BF16) ((unsigned short*)Cout)[off] = f2bf(r);
                else          ((float*)Cout)[off] = r;
            }
        }
    }
}

// ---------------------------------------------------------------------------
// BSR layer: h2[b, r*32+i] = relu( sum_{n in row r} V[n][i,:] . h[b, col[n]*32:+32] + b2 )
// grid = (16 batch tiles of 128) x (64 row blocks). 256 thr = 4 waves,
// wave w handles batch rows w*32..+31 x all 32 out cols = 2x2 frags.
// Per nnz block: stage 128x32 gathered h + 32x32 V, one K=32 MFMA step.
// ---------------------------------------------------------------------------
__global__ __launch_bounds__(256) void bsr_layer(
    const unsigned short* __restrict__ h,     // 2048 x 2048 bf16
    const int* __restrict__ crow,
    const int* __restrict__ cols,
    const unsigned short* __restrict__ vals,  // nnz x 32 x 32 bf16
    const float* __restrict__ b2,
    unsigned short* __restrict__ h2)          // 2048 x 2048 bf16
{
    __shared__ unsigned short Hs[128 * 32];
    __shared__ unsigned short Vs[32 * 32];
    const int t = threadIdx.x;
    const int w = t >> 6;
    const int l = t & 63;
    const int bm = blockIdx.x * 128;
    const int r  = blockIdx.y;
    const int s = crow[r];
    const int e = crow[r + 1];
    const int wrow = w * 32;

    f32x4 acc[2][2];
    #pragma unroll
    for (int i = 0; i < 2; ++i)
        #pragma unroll
        for (int j = 0; j < 2; ++j)
            acc[i][j] = (f32x4){0.f, 0.f, 0.f, 0.f};

    const int rr = t >> 2;
    const int cc = (t & 3) * 8;
    unsigned short* lH0 = Hs + w * 512;
    unsigned short* lH1 = Hs + 2048 + w * 512;
    unsigned short* lV  = Vs + w * 512;
    const int fr = l & 15;
    const int kg = l >> 4;

    for (int n = s; n < e; ++n) {
        const int cb = cols[n];
        const unsigned short* gH = h + (size_t)(bm + rr) * 2048 + cb * 32 + cc;
        async16(gH, lH0);
        async16(gH + (size_t)64 * 2048, lH1);
        if (w < 2)
            async16(vals + (size_t)n * 1024 + t * 8, lV);
        __syncthreads();

        bf16x8 af[2], bg[2];
        #pragma unroll
        for (int i = 0; i < 2; ++i)
            af[i] = *reinterpret_cast<const bf16x8*>(&Hs[(wrow + i * 16 + fr) * 32 + kg * 8]);
        #pragma unroll
        for (int j = 0; j < 2; ++j)
            bg[j] = *reinterpret_cast<const bf16x8*>(&Vs[(j * 16 + fr) * 32 + kg * 8]);
        #pragma unroll
        for (int i = 0; i < 2; ++i)
            #pragma unroll
            for (int j = 0; j < 2; ++j)
                acc[i][j] = __builtin_amdgcn_mfma_f32_16x16x32_bf16(af[i], bg[j], acc[i][j], 0, 0, 0);
        __syncthreads();
    }

    const int fq = l >> 4;
    #pragma unroll
    for (int i = 0; i < 2; ++i) {
        const int row0 = bm + wrow + i * 16 + fq * 4;
        #pragma unroll
        for (int j = 0; j < 2; ++j) {
            const int col = r * 32 + j * 16 + fr;
            const float bv = b2[col];
            #pragma unroll
            for (int v = 0; v < 4; ++v) {
                float rv = fmaxf(acc[i][j][v] + bv, 0.f);
                h2[(size_t)(row0 + v) * 2048 + col] = f2bf(rv);
            }
        }
    }
}

// ---------------------------------------------------------------------------
extern "C" void kernel_launch(void* const* d_in, const int* in_sizes, int n_in,
                              void* d_out, int out_size, void* d_ws, size_t ws_size,
                              hipStream_t stream) {
    const float* x    = (const float*)d_in[0];   // 2048x1024
    const float* W1   = (const float*)d_in[1];   // 2048x1024
    const float* b1   = (const float*)d_in[2];   // 2048
    const int*   crow = (const int*)d_in[3];     // 65
    const int*   cols = (const int*)d_in[4];     // 2048
    const float* vals = (const float*)d_in[5];   // 2048x32x32
    const float* b2   = (const float*)d_in[6];   // 2048
    const float* W3   = (const float*)d_in[7];   // 1024x2048
    const float* b3   = (const float*)d_in[8];   // 1024
    float* out = (float*)d_out;                  // 2048x1024 f32

    const int NE = 2 * 1024 * 1024;              // 2M elems each
    unsigned short* xb  = (unsigned short*)d_ws; // bf16 buffers in ws (~32MB)
    unsigned short* w1b = xb  + NE;
    unsigned short* w3b = w1b + NE;
    unsigned short* vb  = w3b + NE;
    unsigned short* hb  = vb  + NE;              // 4M elems
    unsigned short* h2b = hb  + 2 * NE;          // 4M elems

    cvt_f32_bf16<<<2048, 256, 0, stream>>>(x,    xb,  NE);
    cvt_f32_bf16<<<2048, 256, 0, stream>>>(W1,   w1b, NE);
    cvt_f32_bf16<<<2048, 256, 0, stream>>>(W3,   w3b, NE);
    cvt_f32_bf16<<<2048, 256, 0, stream>>>(vals, vb,  NE);

    // L1: h = relu(x @ W1^T + b1)   M=2048 N=2048 K=1024
    gemm_bt<1, 1><<<dim3(16, 16), 256, 0, stream>>>(xb, w1b, b1, hb, 2048, 2048, 1024);
    // L2: BSR + relu
    bsr_layer<<<dim3(16, 64), 256, 0, stream>>>(hb, crow, cols, vb, b2, h2b);
    // L3: out = h2 @ W3^T + b3      M=2048 N=1024 K=2048
    gemm_bt<0, 0><<<dim3(16, 8), 256, 0, stream>>>(h2b, w3b, b3, out, 2048, 1024, 2048);

    (void)in_sizes; (void)n_in; (void)out_size; (void)ws_size;
}

// Round 2
// 96.914 us; speedup vs baseline: 1.1565x; 1.1565x over previous
//
#include <hip/hip_runtime.h>
#include <hip/hip_bf16.h>

// ---------------------------------------------------------------------------
// BlockedMLP: out = (relu(bsr(relu(x@W1^T+b1))+b2)) @ W3^T + b3
// B=2048, IN=1024, H=2048, OUT=1024, BS=32, RB=CB=64, 32 blocks/row
// Round 2: 2-phase double-buffered pipeline (1 block/CU regime -> explicit
// dbuf required), BK=64 with XOR bank-swizzle (T2, both-sides rule 21),
// L3 re-tiled 128x64 so grid fills all 256 CUs, BSR dbuf, fused cvt.
// ---------------------------------------------------------------------------

typedef __attribute__((ext_vector_type(8))) short bf16x8;
typedef __attribute__((ext_vector_type(4))) float f32x4;

__device__ __forceinline__ unsigned short f2bf(float f) {
    union { float f; unsigned int u; } c; c.f = f;
    unsigned int u = c.u;
    u += 0x7fffu + ((u >> 16) & 1u);   // round-to-nearest-even
    return (unsigned short)(u >> 16);
}

__device__ __forceinline__ void async16(const void* g, void* l) {
    __builtin_amdgcn_global_load_lds(
        (const __attribute__((address_space(1))) void*)g,
        (__attribute__((address_space(3))) void*)l,
        16, 0, 0);
}

// ---------------------------------------------------------------------------
// fused f32 -> bf16 conversion of all 4 inputs (each exactly 2^21 elems)
// ---------------------------------------------------------------------------
__global__ __launch_bounds__(256) void cvt4(
    const float* __restrict__ x,  const float* __restrict__ w1,
    const float* __restrict__ w3, const float* __restrict__ v,
    unsigned short* __restrict__ xb,  unsigned short* __restrict__ w1b,
    unsigned short* __restrict__ w3b, unsigned short* __restrict__ vb)
{
    const int NE = 1 << 21;
    int e = (blockIdx.x * 256 + threadIdx.x) * 4;
    int a = e >> 21;                 // uniform within a block
    int off = e & (NE - 1);
    const float* src = (a == 0) ? x : (a == 1) ? w1 : (a == 2) ? w3 : v;
    unsigned short* dst = (a == 0) ? xb : (a == 1) ? w1b : (a == 2) ? w3b : vb;
    float4 vv = *reinterpret_cast<const float4*>(src + off);
    ushort4 o;
    o.x = f2bf(vv.x); o.y = f2bf(vv.y); o.z = f2bf(vv.z); o.w = f2bf(vv.w);
    *reinterpret_cast<ushort4*>(dst + off) = o;
}

// ---------------------------------------------------------------------------
// bf16 GEMM, B^T form: C[M,N] = A[M,K] x B[N,K]^T + bias, optional relu.
// BM x BN tile, BK=64, 256 threads = 4 waves (2x2), double-buffered LDS,
// 2-phase pipeline: STAGE(next) -> COMPUTE(cur) -> barrier (one drain/step).
// LDS rows are 128B: XOR-swizzle chunk^(row&7) on both staging-source and
// ds_read (rule 21: linear global_load_lds dest + pre-swizzled source).
// ---------------------------------------------------------------------------
template<int BM, int BN, int RELU, int OUT_BF16>
__global__ __launch_bounds__(256) void gemm_bt(
    const unsigned short* __restrict__ A,
    const unsigned short* __restrict__ B,
    const float* __restrict__ bias,
    void* __restrict__ Cout,
    int M, int N, int K)
{
    constexpr int BK = 64;                 // elems; 128B per row
    constexpr int MR = BM / 32;            // MFMA frag repeats per wave
    constexpr int NR = BN / 32;
    constexpr int AI = BM / 32;            // staging instrs per wave (A)
    constexpr int BI = BN / 32;
    __shared__ unsigned short As[2][BM * BK];
    __shared__ unsigned short Bs[2][BN * BK];

    const int t = threadIdx.x;
    const int w = t >> 6;
    const int l = t & 63;
    const int bm = blockIdx.x * BM;
    const int bn = blockIdx.y * BN;
    const int wm = (w >> 1) * (BM / 2);
    const int wn = (w & 1) * (BN / 2);

    f32x4 acc[MR][NR];
    #pragma unroll
    for (int i = 0; i < MR; ++i)
        #pragma unroll
        for (int j = 0; j < NR; ++j)
            acc[i][j] = (f32x4){0.f, 0.f, 0.f, 0.f};

    // staging geometry: instr i of wave w covers tile rows w*(BM/4)+i*8 .. +7
    // lane l -> row +(l>>3), physical 16B chunk (l&7); source column chunk is
    // pre-swizzled: lc = (l&7) ^ (l>>3)   (row&7 == l>>3 here)
    const int arow = bm + w * (BM / 4) + (l >> 3);
    const int brow = bn + w * (BN / 4) + (l >> 3);
    const int scol = ((l & 7) ^ (l >> 3)) * 8;   // elems

    const int fr = l & 15;       // fragment row (within 16)
    const int kg = l >> 4;       // k-group
    const int fq = l >> 4;

    auto stage = [&](int buf, int kt) {
        const int k0 = kt * BK;
        #pragma unroll
        for (int i = 0; i < AI; ++i)
            async16(A + (size_t)(arow + i * 8) * K + k0 + scol,
                    &As[buf][(w * (BM / 4) + i * 8) * BK]);
        #pragma unroll
        for (int i = 0; i < BI; ++i)
            async16(B + (size_t)(brow + i * 8) * K + k0 + scol,
                    &Bs[buf][(w * (BN / 4) + i * 8) * BK]);
    };

    auto compute = [&](int buf) {
        #pragma unroll
        for (int kk = 0; kk < 2; ++kk) {
            const int pc = ((kk * 4 + kg) ^ (fr & 7)) * 8;  // swizzled chunk
            bf16x8 af[MR], bg[NR];
            #pragma unroll
            for (int i = 0; i < MR; ++i)
                af[i] = *reinterpret_cast<const bf16x8*>(
                    &As[buf][(wm + i * 16 + fr) * BK + pc]);
            #pragma unroll
            for (int j = 0; j < NR; ++j)
                bg[j] = *reinterpret_cast<const bf16x8*>(
                    &Bs[buf][(wn + j * 16 + fr) * BK + pc]);
            #pragma unroll
            for (int i = 0; i < MR; ++i)
                #pragma unroll
                for (int j = 0; j < NR; ++j)
                    acc[i][j] = __builtin_amdgcn_mfma_f32_16x16x32_bf16(
                        af[i], bg[j], acc[i][j], 0, 0, 0);
        }
    };

    const int nK = K >> 6;
    int cur = 0;
    stage(0, 0);
    __syncthreads();
    for (int kt = 0; kt < nK - 1; ++kt) {
        stage(cur ^ 1, kt + 1);    // next tile in flight during compute
        compute(cur);
        __syncthreads();           // single vmcnt drain per K-step
        cur ^= 1;
    }
    compute(cur);

    // epilogue: C/D layout col = l&15, row = (l>>4)*4 + v
    #pragma unroll
    for (int i = 0; i < MR; ++i) {
        const int row0 = bm + wm + i * 16 + fq * 4;
        #pragma unroll
        for (int j = 0; j < NR; ++j) {
            const int col = bn + wn + j * 16 + fr;
            const float bv = bias[col];
            #pragma unroll
            for (int v = 0; v < 4; ++v) {
                float r = acc[i][j][v] + bv;
                if (RELU) r = fmaxf(r, 0.f);
                const size_t off = (size_t)(row0 + v) * N + col;
                if (OUT_BF16) ((unsigned short*)Cout)[off] = f2bf(r);
                else          ((float*)Cout)[off] = r;
            }
        }
    }
}

// ---------------------------------------------------------------------------
// BSR layer, double-buffered. grid = (16 batch tiles of 128) x (64 rowblocks).
// 4 waves; wave w owns batch rows w*32..+31 x all 32 out cols (2x2 frags).
// cols[] preloaded to LDS so stage-address latency is uniform and short.
// ---------------------------------------------------------------------------
__global__ __launch_bounds__(256) void bsr_layer(
    const unsigned short* __restrict__ h,     // 2048 x 2048 bf16
    const int* __restrict__ crow,
    const int* __restrict__ cols,
    const unsigned short* __restrict__ vals,  // nnz x 32 x 32 bf16
    const float* __restrict__ b2,
    unsigned short* __restrict__ h2)          // 2048 x 2048 bf16
{
    __shared__ unsigned short Hs[2][128 * 32];
    __shared__ unsigned short Vs[2][32 * 32];
    __shared__ int colsS[64];
    const int t = threadIdx.x;
    const int w = t >> 6;
    const int l = t & 63;
    const int bm = blockIdx.x * 128;
    const int r  = blockIdx.y;
    const int s = crow[r];
    const int cnt = crow[r + 1] - s;
    const int wrow = w * 32;

    if (t < cnt) colsS[t] = cols[s + t];

    f32x4 acc[2][2];
    #pragma unroll
    for (int i = 0; i < 2; ++i)
        #pragma unroll
        for (int j = 0; j < 2; ++j)
            acc[i][j] = (f32x4){0.f, 0.f, 0.f, 0.f};

    const int fr = l & 15;
    const int kg = l >> 4;

    auto stage = [&](int buf, int j) {
        const int cb = colsS[j];
        #pragma unroll
        for (int i = 0; i < 2; ++i)
            async16(h + (size_t)(bm + wrow + i * 16 + (l >> 2)) * 2048 + cb * 32 + (l & 3) * 8,
                    &Hs[buf][(wrow + i * 16) * 32]);
        if (w < 2)
            async16(vals + (size_t)(s + j) * 1024 + t * 8, &Vs[buf][w * 512]);
    };

    auto compute = [&](int buf) {
        bf16x8 af[2], bg[2];
        #pragma unroll
        for (int i = 0; i < 2; ++i)
            af[i] = *reinterpret_cast<const bf16x8*>(
                &Hs[buf][(wrow + i * 16 + fr) * 32 + kg * 8]);
        #pragma unroll
        for (int j = 0; j < 2; ++j)
            bg[j] = *reinterpret_cast<const bf16x8*>(
                &Vs[buf][(j * 16 + fr) * 32 + kg * 8]);
        #pragma unroll
        for (int i = 0; i < 2; ++i)
            #pragma unroll
            for (int j = 0; j < 2; ++j)
                acc[i][j] = __builtin_amdgcn_mfma_f32_16x16x32_bf16(
                    af[i], bg[j], acc[i][j], 0, 0, 0);
    };

    __syncthreads();               // colsS visible
    int cur = 0;
    stage(0, 0);
    __syncthreads();
    for (int j = 0; j < cnt - 1; ++j) {
        stage(cur ^ 1, j + 1);
        compute(cur);
        __syncthreads();
        cur ^= 1;
    }
    compute(cur);

    const int fq = l >> 4;
    #pragma unroll
    for (int i = 0; i < 2; ++i) {
        const int row0 = bm + wrow + i * 16 + fq * 4;
        #pragma unroll
        for (int j = 0; j < 2; ++j) {
            const int col = r * 32 + j * 16 + fr;
            const float bv = b2[col];
            #pragma unroll
            for (int v = 0; v < 4; ++v) {
                float rv = fmaxf(acc[i][j][v] + bv, 0.f);
                h2[(size_t)(row0 + v) * 2048 + col] = f2bf(rv);
            }
        }
    }
}

// ---------------------------------------------------------------------------
extern "C" void kernel_launch(void* const* d_in, const int* in_sizes, int n_in,
                              void* d_out, int out_size, void* d_ws, size_t ws_size,
                              hipStream_t stream) {
    const float* x    = (const float*)d_in[0];   // 2048x1024
    const float* W1   = (const float*)d_in[1];   // 2048x1024
    const float* b1   = (const float*)d_in[2];   // 2048
    const int*   crow = (const int*)d_in[3];     // 65
    const int*   cols = (const int*)d_in[4];     // 2048
    const float* vals = (const float*)d_in[5];   // 2048x32x32
    const float* b2   = (const float*)d_in[6];   // 2048
    const float* W3   = (const float*)d_in[7];   // 1024x2048
    const float* b3   = (const float*)d_in[8];   // 1024
    float* out = (float*)d_out;                  // 2048x1024 f32

    const int NE = 2 * 1024 * 1024;
    unsigned short* xb  = (unsigned short*)d_ws;
    unsigned short* w1b = xb  + NE;
    unsigned short* w3b = w1b + NE;
    unsigned short* vb  = w3b + NE;
    unsigned short* hb  = vb  + NE;              // 4M elems
    unsigned short* h2b = hb  + 2 * NE;          // 4M elems

    cvt4<<<8192, 256, 0, stream>>>(x, W1, W3, vals, xb, w1b, w3b, vb);

    // L1: h = relu(x @ W1^T + b1)   M=2048 N=2048 K=1024, grid 16x16
    gemm_bt<128, 128, 1, 1><<<dim3(16, 16), 256, 0, stream>>>(
        xb, w1b, b1, hb, 2048, 2048, 1024);
    // L2: BSR + relu, grid 16x64
    bsr_layer<<<dim3(16, 64), 256, 0, stream>>>(hb, crow, cols, vb, b2, h2b);
    // L3: out = h2 @ W3^T + b3      M=2048 N=1024 K=2048, tile 128x64, grid 16x16
    gemm_bt<128, 64, 0, 0><<<dim3(16, 16), 256, 0, stream>>>(
        h2b, w3b, b3, out, 2048, 1024, 2048);

    (void)in_sizes; (void)n_in; (void)out_size; (void)ws_size;
}

// Round 3
// 84.569 us; speedup vs baseline: 1.3253x; 1.1460x over previous
//
#include <hip/hip_runtime.h>
#include <hip/hip_bf16.h>

// ---------------------------------------------------------------------------
// BlockedMLP: out = (relu(bsr(relu(x@W1^T+b1))+b2)) @ W3^T + b3
// B=2048, IN=1024, H=2048, OUT=1024, BS=32, RB=CB=64, 32 blocks/row
// Round 3: TLP fix — 2+ blocks/CU everywhere (L1 128x64 grid 512,
// L3 64x64 grid 512, BSR 4/CU), BSR does 2 nnz per K-step (128B LDS rows
// + XOR swizzle -> conflict-free, half the barriers).
// ---------------------------------------------------------------------------

typedef __attribute__((ext_vector_type(8))) short bf16x8;
typedef __attribute__((ext_vector_type(4))) float f32x4;

__device__ __forceinline__ unsigned short f2bf(float f) {
    union { float f; unsigned int u; } c; c.f = f;
    unsigned int u = c.u;
    u += 0x7fffu + ((u >> 16) & 1u);   // round-to-nearest-even
    return (unsigned short)(u >> 16);
}

__device__ __forceinline__ void async16(const void* g, void* l) {
    __builtin_amdgcn_global_load_lds(
        (const __attribute__((address_space(1))) void*)g,
        (__attribute__((address_space(3))) void*)l,
        16, 0, 0);
}

// ---------------------------------------------------------------------------
// fused f32 -> bf16 conversion of all 4 inputs (each exactly 2^21 elems)
// ---------------------------------------------------------------------------
__global__ __launch_bounds__(256) void cvt4(
    const float* __restrict__ x,  const float* __restrict__ w1,
    const float* __restrict__ w3, const float* __restrict__ v,
    unsigned short* __restrict__ xb,  unsigned short* __restrict__ w1b,
    unsigned short* __restrict__ w3b, unsigned short* __restrict__ vb)
{
    const int NE = 1 << 21;
    int e = (blockIdx.x * 256 + threadIdx.x) * 4;
    int a = e >> 21;                 // uniform within a block
    int off = e & (NE - 1);
    const float* src = (a == 0) ? x : (a == 1) ? w1 : (a == 2) ? w3 : v;
    unsigned short* dst = (a == 0) ? xb : (a == 1) ? w1b : (a == 2) ? w3b : vb;
    float4 vv = *reinterpret_cast<const float4*>(src + off);
    ushort4 o;
    o.x = f2bf(vv.x); o.y = f2bf(vv.y); o.z = f2bf(vv.z); o.w = f2bf(vv.w);
    *reinterpret_cast<ushort4*>(dst + off) = o;
}

// ---------------------------------------------------------------------------
// bf16 GEMM, B^T form: C[M,N] = A[M,K] x B[N,K]^T + bias, optional relu.
// BM x BN tile, BK=64, 256 threads = 4 waves (2x2), double-buffered LDS,
// 2-phase pipeline. XOR swizzle chunk^(row&7) on staging-source + ds_read.
// ---------------------------------------------------------------------------
template<int BM, int BN, int RELU, int OUT_BF16>
__global__ __launch_bounds__(256) void gemm_bt(
    const unsigned short* __restrict__ A,
    const unsigned short* __restrict__ B,
    const float* __restrict__ bias,
    void* __restrict__ Cout,
    int M, int N, int K)
{
    constexpr int BK = 64;                 // elems; 128B per row
    constexpr int MR = BM / 32;            // MFMA frag repeats per wave
    constexpr int NR = BN / 32;
    constexpr int AI = BM / 32;            // staging instrs per wave (A)
    constexpr int BI = BN / 32;
    __shared__ unsigned short As[2][BM * BK];
    __shared__ unsigned short Bs[2][BN * BK];

    const int t = threadIdx.x;
    const int w = t >> 6;
    const int l = t & 63;
    const int bm = blockIdx.x * BM;
    const int bn = blockIdx.y * BN;
    const int wm = (w >> 1) * (BM / 2);
    const int wn = (w & 1) * (BN / 2);

    f32x4 acc[MR][NR];
    #pragma unroll
    for (int i = 0; i < MR; ++i)
        #pragma unroll
        for (int j = 0; j < NR; ++j)
            acc[i][j] = (f32x4){0.f, 0.f, 0.f, 0.f};

    // staging: instr i of wave w covers tile rows w*(BM/4)+i*8 + (l>>3);
    // lane chunk (l&7); swizzled source chunk = (l&7) ^ (row&7), row&7==l>>3
    const int arow = bm + w * (BM / 4) + (l >> 3);
    const int brow = bn + w * (BN / 4) + (l >> 3);
    const int scol = ((l & 7) ^ (l >> 3)) * 8;   // elems

    const int fr = l & 15;       // fragment row (within 16)
    const int kg = l >> 4;       // k-group
    const int fq = l >> 4;

    auto stage = [&](int buf, int kt) {
        const int k0 = kt * BK;
        #pragma unroll
        for (int i = 0; i < AI; ++i)
            async16(A + (size_t)(arow + i * 8) * K + k0 + scol,
                    &As[buf][(w * (BM / 4) + i * 8) * BK]);
        #pragma unroll
        for (int i = 0; i < BI; ++i)
            async16(B + (size_t)(brow + i * 8) * K + k0 + scol,
                    &Bs[buf][(w * (BN / 4) + i * 8) * BK]);
    };

    auto compute = [&](int buf) {
        #pragma unroll
        for (int kk = 0; kk < 2; ++kk) {
            const int pc = ((kk * 4 + kg) ^ (fr & 7)) * 8;  // swizzled chunk
            bf16x8 af[MR], bg[NR];
            #pragma unroll
            for (int i = 0; i < MR; ++i)
                af[i] = *reinterpret_cast<const bf16x8*>(
                    &As[buf][(wm + i * 16 + fr) * BK + pc]);
            #pragma unroll
            for (int j = 0; j < NR; ++j)
                bg[j] = *reinterpret_cast<const bf16x8*>(
                    &Bs[buf][(wn + j * 16 + fr) * BK + pc]);
            #pragma unroll
            for (int i = 0; i < MR; ++i)
                #pragma unroll
                for (int j = 0; j < NR; ++j)
                    acc[i][j] = __builtin_amdgcn_mfma_f32_16x16x32_bf16(
                        af[i], bg[j], acc[i][j], 0, 0, 0);
        }
    };

    const int nK = K >> 6;
    int cur = 0;
    stage(0, 0);
    __syncthreads();
    for (int kt = 0; kt < nK - 1; ++kt) {
        stage(cur ^ 1, kt + 1);    // next tile in flight during compute
        compute(cur);
        __syncthreads();           // single vmcnt drain per K-step
        cur ^= 1;
    }
    compute(cur);

    // epilogue: C/D layout col = l&15, row = (l>>4)*4 + v
    #pragma unroll
    for (int i = 0; i < MR; ++i) {
        const int row0 = bm + wm + i * 16 + fq * 4;
        #pragma unroll
        for (int j = 0; j < NR; ++j) {
            const int col = bn + wn + j * 16 + fr;
            const float bv = bias[col];
            #pragma unroll
            for (int v = 0; v < 4; ++v) {
                float r = acc[i][j][v] + bv;
                if (RELU) r = fmaxf(r, 0.f);
                const size_t off = (size_t)(row0 + v) * N + col;
                if (OUT_BF16) ((unsigned short*)Cout)[off] = f2bf(r);
                else          ((float*)Cout)[off] = r;
            }
        }
    }
}

// ---------------------------------------------------------------------------
// BSR layer: 2 nnz blocks per K-step (K-concat). grid = (16 batch tiles of
// 128) x (64 rowblocks) = 1024 blocks (4/CU). LDS rows 128B, XOR-swizzled.
// Wave w owns batch rows w*32..+31 x all 32 out cols (2x2 frags, BK=64).
// ---------------------------------------------------------------------------
__global__ __launch_bounds__(256) void bsr_layer(
    const unsigned short* __restrict__ h,     // 2048 x 2048 bf16
    const int* __restrict__ crow,
    const int* __restrict__ cols,
    const unsigned short* __restrict__ vals,  // nnz x 32 x 32 bf16
    const float* __restrict__ b2,
    unsigned short* __restrict__ h2)          // 2048 x 2048 bf16
{
    __shared__ unsigned short Hs[2][128 * 64];
    __shared__ unsigned short Vs[2][32 * 64];
    __shared__ int colsS[64];
    const int t = threadIdx.x;
    const int w = t >> 6;
    const int l = t & 63;
    const int bm = blockIdx.x * 128;
    const int r  = blockIdx.y;
    const int s = crow[r];
    const int cnt = crow[r + 1] - s;
    const int wrow = w * 32;

    if (t < cnt) colsS[t] = cols[s + t];

    f32x4 acc[2][2];
    #pragma unroll
    for (int i = 0; i < 2; ++i)
        #pragma unroll
        for (int j = 0; j < 2; ++j)
            acc[i][j] = (f32x4){0.f, 0.f, 0.f, 0.f};

    const int fr = l & 15;
    const int kg = l >> 4;
    const int lr = l >> 3;               // staging row-in-group
    const int sc = (l & 7) ^ lr;         // swizzled source chunk

    auto stage = [&](int buf, int js) {
        const int n0 = s + 2 * js;
        const bool tail = (2 * js + 1 >= cnt);
        const int c0 = colsS[2 * js];
        const int c1 = tail ? c0 : colsS[2 * js + 1];
        const int n1 = tail ? n0 : n0 + 1;
        // H gather: 128 rows x 128B; per wave 4 instrs of 8 rows
        #pragma unroll
        for (int i = 0; i < 4; ++i) {
            const int row = bm + w * 32 + i * 8 + lr;
            const int col = (sc & 4) ? c1 * 32 + (sc & 3) * 8 : c0 * 32 + sc * 8;
            async16(h + (size_t)row * 2048 + col,
                    &Hs[buf][(w * 32 + i * 8) * 64]);
        }
        // V: 32 rows x 128B; 1 instr per wave (8 rows each)
        const int vrow = w * 8 + lr;
        if (!tail || !(sc & 4)) {
            const unsigned short* src =
                vals + (size_t)((sc & 4) ? n1 : n0) * 1024 + vrow * 32 + (sc & 3) * 8;
            async16(src, &Vs[buf][(w * 8) * 64]);
        } else {
            // odd tail: zero the upper-K half slots instead of staging
            bf16x8 z = (bf16x8){0,0,0,0,0,0,0,0};
            *reinterpret_cast<bf16x8*>(&Vs[buf][vrow * 64 + (l & 7) * 8]) = z;
        }
    };

    auto compute = [&](int buf) {
        #pragma unroll
        for (int kk = 0; kk < 2; ++kk) {
            const int pc = ((kk * 4 + kg) ^ (fr & 7)) * 8;
            bf16x8 af[2], bg[2];
            #pragma unroll
            for (int i = 0; i < 2; ++i)
                af[i] = *reinterpret_cast<const bf16x8*>(
                    &Hs[buf][(wrow + i * 16 + fr) * 64 + pc]);
            #pragma unroll
            for (int j = 0; j < 2; ++j)
                bg[j] = *reinterpret_cast<const bf16x8*>(
                    &Vs[buf][(j * 16 + fr) * 64 + pc]);
            #pragma unroll
            for (int i = 0; i < 2; ++i)
                #pragma unroll
                for (int j = 0; j < 2; ++j)
                    acc[i][j] = __builtin_amdgcn_mfma_f32_16x16x32_bf16(
                        af[i], bg[j], acc[i][j], 0, 0, 0);
        }
    };

    __syncthreads();               // colsS visible
    const int nsteps = (cnt + 1) >> 1;
    int cur = 0;
    stage(0, 0);
    __syncthreads();
    for (int js = 0; js < nsteps - 1; ++js) {
        stage(cur ^ 1, js + 1);
        compute(cur);
        __syncthreads();
        cur ^= 1;
    }
    compute(cur);

    const int fq = l >> 4;
    #pragma unroll
    for (int i = 0; i < 2; ++i) {
        const int row0 = bm + wrow + i * 16 + fq * 4;
        #pragma unroll
        for (int j = 0; j < 2; ++j) {
            const int col = r * 32 + j * 16 + fr;
            const float bv = b2[col];
            #pragma unroll
            for (int v = 0; v < 4; ++v) {
                float rv = fmaxf(acc[i][j][v] + bv, 0.f);
                h2[(size_t)(row0 + v) * 2048 + col] = f2bf(rv);
            }
        }
    }
}

// ---------------------------------------------------------------------------
extern "C" void kernel_launch(void* const* d_in, const int* in_sizes, int n_in,
                              void* d_out, int out_size, void* d_ws, size_t ws_size,
                              hipStream_t stream) {
    const float* x    = (const float*)d_in[0];   // 2048x1024
    const float* W1   = (const float*)d_in[1];   // 2048x1024
    const float* b1   = (const float*)d_in[2];   // 2048
    const int*   crow = (const int*)d_in[3];     // 65
    const int*   cols = (const int*)d_in[4];     // 2048
    const float* vals = (const float*)d_in[5];   // 2048x32x32
    const float* b2   = (const float*)d_in[6];   // 2048
    const float* W3   = (const float*)d_in[7];   // 1024x2048
    const float* b3   = (const float*)d_in[8];   // 1024
    float* out = (float*)d_out;                  // 2048x1024 f32

    const int NE = 2 * 1024 * 1024;
    unsigned short* xb  = (unsigned short*)d_ws;
    unsigned short* w1b = xb  + NE;
    unsigned short* w3b = w1b + NE;
    unsigned short* vb  = w3b + NE;
    unsigned short* hb  = vb  + NE;              // 4M elems
    unsigned short* h2b = hb  + 2 * NE;          // 4M elems

    cvt4<<<8192, 256, 0, stream>>>(x, W1, W3, vals, xb, w1b, w3b, vb);

    // L1: h = relu(x @ W1^T + b1)   M=2048 N=2048 K=1024, tile 128x64, 512 blks
    gemm_bt<128, 64, 1, 1><<<dim3(16, 32), 256, 0, stream>>>(
        xb, w1b, b1, hb, 2048, 2048, 1024);
    // L2: BSR + relu, grid 16x64 = 1024 blks
    bsr_layer<<<dim3(16, 64), 256, 0, stream>>>(hb, crow, cols, vb, b2, h2b);
    // L3: out = h2 @ W3^T + b3      M=2048 N=1024 K=2048, tile 64x64, 512 blks
    gemm_bt<64, 64, 0, 0><<<dim3(32, 16), 256, 0, stream>>>(
        h2b, w3b, b3, out, 2048, 1024, 2048);

    (void)in_sizes; (void)n_in; (void)out_size; (void)ws_size;
}

// Round 4
// 84.247 us; speedup vs baseline: 1.3304x; 1.0038x over previous
//
#include <hip/hip_runtime.h>
#include <hip/hip_bf16.h>

// ---------------------------------------------------------------------------
// BlockedMLP: out = (relu(bsr(relu(x@W1^T+b1))+b2)) @ W3^T + b3
// B=2048, IN=1024, H=2048, OUT=1024, BS=32, RB=CB=64, 32 blocks/row
// Round 4: XCD-pinned block mapping (xcd = blockIdx % 8 empirical rule) so
// panel re-reads hit the 4MB per-XCD L2 instead of queued HBM. R3 analysis:
// per-K-step latency ~2500cyc from L2 thrash (R1 FETCH 20.5MB vs 8MB ideal).
// ---------------------------------------------------------------------------

typedef __attribute__((ext_vector_type(8))) short bf16x8;
typedef __attribute__((ext_vector_type(4))) float f32x4;

__device__ __forceinline__ unsigned short f2bf(float f) {
    union { float f; unsigned int u; } c; c.f = f;
    unsigned int u = c.u;
    u += 0x7fffu + ((u >> 16) & 1u);   // round-to-nearest-even
    return (unsigned short)(u >> 16);
}

__device__ __forceinline__ void async16(const void* g, void* l) {
    __builtin_amdgcn_global_load_lds(
        (const __attribute__((address_space(1))) void*)g,
        (__attribute__((address_space(3))) void*)l,
        16, 0, 0);
}

// ---------------------------------------------------------------------------
// fused f32 -> bf16 conversion of all 4 inputs (each exactly 2^21 elems)
// ---------------------------------------------------------------------------
__global__ __launch_bounds__(256) void cvt4(
    const float* __restrict__ x,  const float* __restrict__ w1,
    const float* __restrict__ w3, const float* __restrict__ v,
    unsigned short* __restrict__ xb,  unsigned short* __restrict__ w1b,
    unsigned short* __restrict__ w3b, unsigned short* __restrict__ vb)
{
    const int NE = 1 << 21;
    int e = (blockIdx.x * 256 + threadIdx.x) * 4;
    int a = e >> 21;                 // uniform within a block
    int off = e & (NE - 1);
    const float* src = (a == 0) ? x : (a == 1) ? w1 : (a == 2) ? w3 : v;
    unsigned short* dst = (a == 0) ? xb : (a == 1) ? w1b : (a == 2) ? w3b : vb;
    float4 vv = *reinterpret_cast<const float4*>(src + off);
    ushort4 o;
    o.x = f2bf(vv.x); o.y = f2bf(vv.y); o.z = f2bf(vv.z); o.w = f2bf(vv.w);
    *reinterpret_cast<ushort4*>(dst + off) = o;
}

// ---------------------------------------------------------------------------
// bf16 GEMM, B^T form: C[M,N] = A[M,K] x B[N,K]^T + bias, optional relu.
// BM x BN tile, BK=64, 256 threads = 4 waves (2x2), double-buffered LDS,
// 2-phase pipeline, XOR swizzle chunk^(row&7) on staging-source + ds_read.
// 1-D grid, XCD-pinned decode: xcd = id&7 owns m-tiles [xcd*MCL, +MCL).
// Grid size must be (M/BM)*(N/BN) with M/BM == 8*MCL.
// ---------------------------------------------------------------------------
template<int BM, int BN, int MCL, int RELU, int OUT_BF16>
__global__ __launch_bounds__(256) void gemm_bt(
    const unsigned short* __restrict__ A,
    const unsigned short* __restrict__ B,
    const float* __restrict__ bias,
    void* __restrict__ Cout,
    int M, int N, int K)
{
    constexpr int BK = 64;                 // elems; 128B per row
    constexpr int MR = BM / 32;            // MFMA frag repeats per wave
    constexpr int NR = BN / 32;
    constexpr int AI = BM / 32;            // staging instrs per wave (A)
    constexpr int BI = BN / 32;
    __shared__ unsigned short As[2][BM * BK];
    __shared__ unsigned short Bs[2][BN * BK];

    const int t = threadIdx.x;
    const int w = t >> 6;
    const int l = t & 63;

    // XCD-pinned tile decode
    const int id = blockIdx.x;
    const int xcd = id & 7;
    const int j = id >> 3;
    const int mt = xcd * MCL + (j & (MCL - 1));
    const int nt = j / MCL;
    const int bm = mt * BM;
    const int bn = nt * BN;

    const int wm = (w >> 1) * (BM / 2);
    const int wn = (w & 1) * (BN / 2);

    f32x4 acc[MR][NR];
    #pragma unroll
    for (int i = 0; i < MR; ++i)
        #pragma unroll
        for (int jj = 0; jj < NR; ++jj)
            acc[i][jj] = (f32x4){0.f, 0.f, 0.f, 0.f};

    // staging: instr i of wave w covers tile rows w*(BM/4)+i*8 + (l>>3);
    // lane chunk (l&7); swizzled source chunk = (l&7) ^ (row&7), row&7==l>>3
    const int arow = bm + w * (BM / 4) + (l >> 3);
    const int brow = bn + w * (BN / 4) + (l >> 3);
    const int scol = ((l & 7) ^ (l >> 3)) * 8;   // elems

    const int fr = l & 15;       // fragment row (within 16)
    const int kg = l >> 4;       // k-group
    const int fq = l >> 4;

    auto stage = [&](int buf, int kt) {
        const int k0 = kt * BK;
        #pragma unroll
        for (int i = 0; i < AI; ++i)
            async16(A + (size_t)(arow + i * 8) * K + k0 + scol,
                    &As[buf][(w * (BM / 4) + i * 8) * BK]);
        #pragma unroll
        for (int i = 0; i < BI; ++i)
            async16(B + (size_t)(brow + i * 8) * K + k0 + scol,
                    &Bs[buf][(w * (BN / 4) + i * 8) * BK]);
    };

    auto compute = [&](int buf) {
        #pragma unroll
        for (int kk = 0; kk < 2; ++kk) {
            const int pc = ((kk * 4 + kg) ^ (fr & 7)) * 8;  // swizzled chunk
            bf16x8 af[MR], bg[NR];
            #pragma unroll
            for (int i = 0; i < MR; ++i)
                af[i] = *reinterpret_cast<const bf16x8*>(
                    &As[buf][(wm + i * 16 + fr) * BK + pc]);
            #pragma unroll
            for (int jj = 0; jj < NR; ++jj)
                bg[jj] = *reinterpret_cast<const bf16x8*>(
                    &Bs[buf][(wn + jj * 16 + fr) * BK + pc]);
            #pragma unroll
            for (int i = 0; i < MR; ++i)
                #pragma unroll
                for (int jj = 0; jj < NR; ++jj)
                    acc[i][jj] = __builtin_amdgcn_mfma_f32_16x16x32_bf16(
                        af[i], bg[jj], acc[i][jj], 0, 0, 0);
        }
    };

    const int nK = K >> 6;
    int cur = 0;
    stage(0, 0);
    __syncthreads();
    for (int kt = 0; kt < nK - 1; ++kt) {
        stage(cur ^ 1, kt + 1);    // next tile in flight during compute
        compute(cur);
        __syncthreads();           // single vmcnt drain per K-step
        cur ^= 1;
    }
    compute(cur);

    // epilogue: C/D layout col = l&15, row = (l>>4)*4 + v
    #pragma unroll
    for (int i = 0; i < MR; ++i) {
        const int row0 = bm + wm + i * 16 + fq * 4;
        #pragma unroll
        for (int jj = 0; jj < NR; ++jj) {
            const int col = bn + wn + jj * 16 + fr;
            const float bv = bias[col];
            #pragma unroll
            for (int v = 0; v < 4; ++v) {
                float r = acc[i][jj][v] + bv;
                if (RELU) r = fmaxf(r, 0.f);
                const size_t off = (size_t)(row0 + v) * N + col;
                if (OUT_BF16) ((unsigned short*)Cout)[off] = f2bf(r);
                else          ((float*)Cout)[off] = r;
            }
        }
    }
}

// ---------------------------------------------------------------------------
// BSR layer: 2 nnz blocks per K-step (K-concat). 1-D grid 1024, XCD-pinned:
// xcd owns batch-tiles {2*xcd, 2*xcd+1} (H slice 1MB -> L2-resident).
// LDS rows 128B, XOR-swizzled. Wave w owns batch rows w*32..+31 (2x2 frags).
// ---------------------------------------------------------------------------
__global__ __launch_bounds__(256) void bsr_layer(
    const unsigned short* __restrict__ h,     // 2048 x 2048 bf16
    const int* __restrict__ crow,
    const int* __restrict__ cols,
    const unsigned short* __restrict__ vals,  // nnz x 32 x 32 bf16
    const float* __restrict__ b2,
    unsigned short* __restrict__ h2)          // 2048 x 2048 bf16
{
    __shared__ unsigned short Hs[2][128 * 64];
    __shared__ unsigned short Vs[2][32 * 64];
    __shared__ int colsS[64];
    const int t = threadIdx.x;
    const int w = t >> 6;
    const int l = t & 63;

    // XCD-pinned decode: 1024 blocks; bt in {2*xcd, 2*xcd+1}, r = all 64
    const int id = blockIdx.x;
    const int xcd = id & 7;
    const int j2 = id >> 3;
    const int bt = xcd * 2 + (j2 & 1);
    const int r  = j2 >> 1;
    const int bm = bt * 128;

    const int s = crow[r];
    const int cnt = crow[r + 1] - s;
    const int wrow = w * 32;

    if (t < cnt) colsS[t] = cols[s + t];

    f32x4 acc[2][2];
    #pragma unroll
    for (int i = 0; i < 2; ++i)
        #pragma unroll
        for (int jj = 0; jj < 2; ++jj)
            acc[i][jj] = (f32x4){0.f, 0.f, 0.f, 0.f};

    const int fr = l & 15;
    const int kg = l >> 4;
    const int lr = l >> 3;               // staging row-in-group
    const int sc = (l & 7) ^ lr;         // swizzled source chunk

    auto stage = [&](int buf, int js) {
        const int n0 = s + 2 * js;
        const bool tail = (2 * js + 1 >= cnt);
        const int c0 = colsS[2 * js];
        const int c1 = tail ? c0 : colsS[2 * js + 1];
        const int n1 = tail ? n0 : n0 + 1;
        // H gather: 128 rows x 128B; per wave 4 instrs of 8 rows
        #pragma unroll
        for (int i = 0; i < 4; ++i) {
            const int row = bm + w * 32 + i * 8 + lr;
            const int col = (sc & 4) ? c1 * 32 + (sc & 3) * 8 : c0 * 32 + sc * 8;
            async16(h + (size_t)row * 2048 + col,
                    &Hs[buf][(w * 32 + i * 8) * 64]);
        }
        // V: 32 rows x 128B; 1 instr per wave (8 rows each)
        const int vrow = w * 8 + lr;
        if (!tail || !(sc & 4)) {
            const unsigned short* src =
                vals + (size_t)((sc & 4) ? n1 : n0) * 1024 + vrow * 32 + (sc & 3) * 8;
            async16(src, &Vs[buf][(w * 8) * 64]);
        } else {
            bf16x8 z = (bf16x8){0,0,0,0,0,0,0,0};
            *reinterpret_cast<bf16x8*>(&Vs[buf][vrow * 64 + (l & 7) * 8]) = z;
        }
    };

    auto compute = [&](int buf) {
        #pragma unroll
        for (int kk = 0; kk < 2; ++kk) {
            const int pc = ((kk * 4 + kg) ^ (fr & 7)) * 8;
            bf16x8 af[2], bg[2];
            #pragma unroll
            for (int i = 0; i < 2; ++i)
                af[i] = *reinterpret_cast<const bf16x8*>(
                    &Hs[buf][(wrow + i * 16 + fr) * 64 + pc]);
            #pragma unroll
            for (int jj = 0; jj < 2; ++jj)
                bg[jj] = *reinterpret_cast<const bf16x8*>(
                    &Vs[buf][(jj * 16 + fr) * 64 + pc]);
            #pragma unroll
            for (int i = 0; i < 2; ++i)
                #pragma unroll
                for (int jj = 0; jj < 2; ++jj)
                    acc[i][jj] = __builtin_amdgcn_mfma_f32_16x16x32_bf16(
                        af[i], bg[jj], acc[i][jj], 0, 0, 0);
        }
    };

    __syncthreads();               // colsS visible
    const int nsteps = (cnt + 1) >> 1;
    int cur = 0;
    stage(0, 0);
    __syncthreads();
    for (int js = 0; js < nsteps - 1; ++js) {
        stage(cur ^ 1, js + 1);
        compute(cur);
        __syncthreads();
        cur ^= 1;
    }
    compute(cur);

    const int fq = l >> 4;
    #pragma unroll
    for (int i = 0; i < 2; ++i) {
        const int row0 = bm + wrow + i * 16 + fq * 4;
        #pragma unroll
        for (int jj = 0; jj < 2; ++jj) {
            const int col = r * 32 + jj * 16 + fr;
            const float bv = b2[col];
            #pragma unroll
            for (int v = 0; v < 4; ++v) {
                float rv = fmaxf(acc[i][jj][v] + bv, 0.f);
                h2[(size_t)(row0 + v) * 2048 + col] = f2bf(rv);
            }
        }
    }
}

// ---------------------------------------------------------------------------
extern "C" void kernel_launch(void* const* d_in, const int* in_sizes, int n_in,
                              void* d_out, int out_size, void* d_ws, size_t ws_size,
                              hipStream_t stream) {
    const float* x    = (const float*)d_in[0];   // 2048x1024
    const float* W1   = (const float*)d_in[1];   // 2048x1024
    const float* b1   = (const float*)d_in[2];   // 2048
    const int*   crow = (const int*)d_in[3];     // 65
    const int*   cols = (const int*)d_in[4];     // 2048
    const float* vals = (const float*)d_in[5];   // 2048x32x32
    const float* b2   = (const float*)d_in[6];   // 2048
    const float* W3   = (const float*)d_in[7];   // 1024x2048
    const float* b3   = (const float*)d_in[8];   // 1024
    float* out = (float*)d_out;                  // 2048x1024 f32

    const int NE = 2 * 1024 * 1024;
    unsigned short* xb  = (unsigned short*)d_ws;
    unsigned short* w1b = xb  + NE;
    unsigned short* w3b = w1b + NE;
    unsigned short* vb  = w3b + NE;
    unsigned short* hb  = vb  + NE;              // 4M elems
    unsigned short* h2b = hb  + 2 * NE;          // 4M elems

    cvt4<<<8192, 256, 0, stream>>>(x, W1, W3, vals, xb, w1b, w3b, vb);

    // L1: h = relu(x @ W1^T + b1)  M=2048 N=2048 K=1024, tile 128x64,
    // 16 m-tiles = 8 XCD x 2, 32 n-tiles -> grid 512
    gemm_bt<128, 64, 2, 1, 1><<<512, 256, 0, stream>>>(
        xb, w1b, b1, hb, 2048, 2048, 1024);
    // L2: BSR + relu, grid 1024, bt pinned per XCD
    bsr_layer<<<1024, 256, 0, stream>>>(hb, crow, cols, vb, b2, h2b);
    // L3: out = h2 @ W3^T + b3  M=2048 N=1024 K=2048, tile 64x64,
    // 32 m-tiles = 8 XCD x 4, 16 n-tiles -> grid 512
    gemm_bt<64, 64, 4, 0, 0><<<512, 256, 0, stream>>>(
        h2b, w3b, b3, out, 2048, 1024, 2048);

    (void)in_sizes; (void)n_in; (void)out_size; (void)ws_size;
}

// Round 5
// 79.578 us; speedup vs baseline: 1.4084x; 1.0587x over previous
//
#include <hip/hip_runtime.h>
#include <hip/hip_bf16.h>

// ---------------------------------------------------------------------------
// BlockedMLP: out = (relu(bsr(relu(x@W1^T+b1))+b2)) @ W3^T + b3
// B=2048, IN=1024, H=2048, OUT=1024, BS=32, RB=CB=64, 32 blocks/row
// Round 5: T3/T4 counted-vmcnt pipeline. Raw s_barrier + s_waitcnt vmcnt(LPS)
// replaces __syncthreads(); stage(kt+2) issued AFTER compute so its loads
// span a full iteration (loads never drained to 0 in the main loop).
// ---------------------------------------------------------------------------

typedef __attribute__((ext_vector_type(8))) short bf16x8;
typedef __attribute__((ext_vector_type(4))) float f32x4;

__device__ __forceinline__ unsigned short f2bf(float f) {
    union { float f; unsigned int u; } c; c.f = f;
    unsigned int u = c.u;
    u += 0x7fffu + ((u >> 16) & 1u);   // round-to-nearest-even
    return (unsigned short)(u >> 16);
}

__device__ __forceinline__ void async16(const void* g, void* l) {
    __builtin_amdgcn_global_load_lds(
        (const __attribute__((address_space(1))) void*)g,
        (__attribute__((address_space(3))) void*)l,
        16, 0, 0);
}

template<int N>
__device__ __forceinline__ void vm_wait() {
    asm volatile("s_waitcnt vmcnt(%0)" :: "n"(N) : "memory");
}
__device__ __forceinline__ void barrier() {
    asm volatile("" ::: "memory");
    __builtin_amdgcn_s_barrier();
    asm volatile("" ::: "memory");
}

// ---------------------------------------------------------------------------
// fused f32 -> bf16 conversion of all 4 inputs (each exactly 2^21 elems)
// ---------------------------------------------------------------------------
__global__ __launch_bounds__(256) void cvt4(
    const float* __restrict__ x,  const float* __restrict__ w1,
    const float* __restrict__ w3, const float* __restrict__ v,
    unsigned short* __restrict__ xb,  unsigned short* __restrict__ w1b,
    unsigned short* __restrict__ w3b, unsigned short* __restrict__ vb)
{
    const int NE = 1 << 21;
    int e = (blockIdx.x * 256 + threadIdx.x) * 4;
    int a = e >> 21;                 // uniform within a block
    int off = e & (NE - 1);
    const float* src = (a == 0) ? x : (a == 1) ? w1 : (a == 2) ? w3 : v;
    unsigned short* dst = (a == 0) ? xb : (a == 1) ? w1b : (a == 2) ? w3b : vb;
    float4 vv = *reinterpret_cast<const float4*>(src + off);
    ushort4 o;
    o.x = f2bf(vv.x); o.y = f2bf(vv.y); o.z = f2bf(vv.z); o.w = f2bf(vv.w);
    *reinterpret_cast<ushort4*>(dst + off) = o;
}

// ---------------------------------------------------------------------------
// bf16 GEMM, B^T form: C[M,N] = A[M,K] x B[N,K]^T + bias, optional relu.
// BM x BN tile, BK=64, 256 threads = 4 waves (2x2), double-buffered LDS,
// counted-vmcnt pipeline (2 stages in flight), XOR swizzle chunk^(row&7).
// 1-D grid, XCD-pinned decode: xcd = id&7 owns m-tiles [xcd*MCL, +MCL).
// ---------------------------------------------------------------------------
template<int BM, int BN, int MCL, int RELU, int OUT_BF16>
__global__ __launch_bounds__(256) void gemm_bt(
    const unsigned short* __restrict__ A,
    const unsigned short* __restrict__ B,
    const float* __restrict__ bias,
    void* __restrict__ Cout,
    int M, int N, int K)
{
    constexpr int BK = 64;                 // elems; 128B per row
    constexpr int MR = BM / 32;            // MFMA frag repeats per wave
    constexpr int NR = BN / 32;
    constexpr int AI = BM / 32;            // staging instrs per thread (A)
    constexpr int BI = BN / 32;
    constexpr int LPS = AI + BI;           // loads per thread per stage
    __shared__ unsigned short As[2][BM * BK];
    __shared__ unsigned short Bs[2][BN * BK];

    const int t = threadIdx.x;
    const int w = t >> 6;
    const int l = t & 63;

    // XCD-pinned tile decode
    const int id = blockIdx.x;
    const int xcd = id & 7;
    const int j = id >> 3;
    const int mt = xcd * MCL + (j & (MCL - 1));
    const int nt = j / MCL;
    const int bm = mt * BM;
    const int bn = nt * BN;

    const int wm = (w >> 1) * (BM / 2);
    const int wn = (w & 1) * (BN / 2);

    f32x4 acc[MR][NR];
    #pragma unroll
    for (int i = 0; i < MR; ++i)
        #pragma unroll
        for (int jj = 0; jj < NR; ++jj)
            acc[i][jj] = (f32x4){0.f, 0.f, 0.f, 0.f};

    // staging: instr i of wave w covers tile rows w*(BM/4)+i*8 + (l>>3);
    // lane chunk (l&7); swizzled source chunk = (l&7) ^ (row&7), row&7==l>>3
    const int arow = bm + w * (BM / 4) + (l >> 3);
    const int brow = bn + w * (BN / 4) + (l >> 3);
    const int scol = ((l & 7) ^ (l >> 3)) * 8;   // elems

    const int fr = l & 15;       // fragment row (within 16)
    const int kg = l >> 4;       // k-group
    const int fq = l >> 4;

    auto stage = [&](int buf, int kt) {
        const int k0 = kt * BK;
        #pragma unroll
        for (int i = 0; i < AI; ++i)
            async16(A + (size_t)(arow + i * 8) * K + k0 + scol,
                    &As[buf][(w * (BM / 4) + i * 8) * BK]);
        #pragma unroll
        for (int i = 0; i < BI; ++i)
            async16(B + (size_t)(brow + i * 8) * K + k0 + scol,
                    &Bs[buf][(w * (BN / 4) + i * 8) * BK]);
    };

    auto compute = [&](int buf) {
        #pragma unroll
        for (int kk = 0; kk < 2; ++kk) {
            const int pc = ((kk * 4 + kg) ^ (fr & 7)) * 8;  // swizzled chunk
            bf16x8 af[MR], bg[NR];
            #pragma unroll
            for (int i = 0; i < MR; ++i)
                af[i] = *reinterpret_cast<const bf16x8*>(
                    &As[buf][(wm + i * 16 + fr) * BK + pc]);
            #pragma unroll
            for (int jj = 0; jj < NR; ++jj)
                bg[jj] = *reinterpret_cast<const bf16x8*>(
                    &Bs[buf][(wn + jj * 16 + fr) * BK + pc]);
            #pragma unroll
            for (int i = 0; i < MR; ++i)
                #pragma unroll
                for (int jj = 0; jj < NR; ++jj)
                    acc[i][jj] = __builtin_amdgcn_mfma_f32_16x16x32_bf16(
                        af[i], bg[jj], acc[i][jj], 0, 0, 0);
        }
    };

    const int nK = K >> 6;                 // >= 16 here
    stage(0, 0);
    stage(1, 1);                           // 2*LPS loads in flight
    int cur = 0;
    for (int kt = 0; kt < nK - 1; ++kt) {
        vm_wait<LPS>();                    // only buf[cur]'s loads done
        barrier();
        compute(cur);
        barrier();
        if (kt + 2 < nK) stage(cur, kt + 2);  // loads span next iteration
        cur ^= 1;
    }
    vm_wait<0>();
    barrier();
    compute(cur);

    // epilogue: C/D layout col = l&15, row = (l>>4)*4 + v
    #pragma unroll
    for (int i = 0; i < MR; ++i) {
        const int row0 = bm + wm + i * 16 + fq * 4;
        #pragma unroll
        for (int jj = 0; jj < NR; ++jj) {
            const int col = bn + wn + jj * 16 + fr;
            const float bv = bias[col];
            #pragma unroll
            for (int v = 0; v < 4; ++v) {
                float r = acc[i][jj][v] + bv;
                if (RELU) r = fmaxf(r, 0.f);
                const size_t off = (size_t)(row0 + v) * N + col;
                if (OUT_BF16) ((unsigned short*)Cout)[off] = f2bf(r);
                else          ((float*)Cout)[off] = r;
            }
        }
    }
}

// ---------------------------------------------------------------------------
// BSR layer: 2 nnz blocks per K-step (K-concat), counted-vmcnt pipeline.
// 1-D grid 1024, XCD-pinned: xcd owns batch-tiles {2*xcd, 2*xcd+1}.
// LDS rows 128B, XOR-swizzled. Wave w owns batch rows w*32..+31 (2x2 frags).
// ---------------------------------------------------------------------------
__global__ __launch_bounds__(256) void bsr_layer(
    const unsigned short* __restrict__ h,     // 2048 x 2048 bf16
    const int* __restrict__ crow,
    const int* __restrict__ cols,
    const unsigned short* __restrict__ vals,  // nnz x 32 x 32 bf16
    const float* __restrict__ b2,
    unsigned short* __restrict__ h2)          // 2048 x 2048 bf16
{
    __shared__ unsigned short Hs[2][128 * 64];
    __shared__ unsigned short Vs[2][32 * 64];
    __shared__ int colsS[64];
    const int t = threadIdx.x;
    const int w = t >> 6;
    const int l = t & 63;

    // XCD-pinned decode: 1024 blocks; bt in {2*xcd, 2*xcd+1}, r = all 64
    const int id = blockIdx.x;
    const int xcd = id & 7;
    const int j2 = id >> 3;
    const int bt = xcd * 2 + (j2 & 1);
    const int r  = j2 >> 1;
    const int bm = bt * 128;

    const int s = crow[r];
    const int cnt = crow[r + 1] - s;
    const int wrow = w * 32;

    if (t < cnt) colsS[t] = cols[s + t];

    f32x4 acc[2][2];
    #pragma unroll
    for (int i = 0; i < 2; ++i)
        #pragma unroll
        for (int jj = 0; jj < 2; ++jj)
            acc[i][jj] = (f32x4){0.f, 0.f, 0.f, 0.f};

    const int fr = l & 15;
    const int kg = l >> 4;
    const int lr = l >> 3;               // staging row-in-group
    const int sc = (l & 7) ^ lr;         // swizzled source chunk

    auto stage = [&](int buf, int js) {
        const int n0 = s + 2 * js;
        const bool tail = (2 * js + 1 >= cnt);
        const int c0 = colsS[2 * js];
        const int c1 = tail ? c0 : colsS[2 * js + 1];
        const int n1 = tail ? n0 : n0 + 1;
        // H gather: 128 rows x 128B; per wave 4 instrs of 8 rows
        #pragma unroll
        for (int i = 0; i < 4; ++i) {
            const int row = bm + w * 32 + i * 8 + lr;
            const int col = (sc & 4) ? c1 * 32 + (sc & 3) * 8 : c0 * 32 + sc * 8;
            async16(h + (size_t)row * 2048 + col,
                    &Hs[buf][(w * 32 + i * 8) * 64]);
        }
        // V: 32 rows x 128B; 1 instr per wave (8 rows each)
        const int vrow = w * 8 + lr;
        if (!tail || !(sc & 4)) {
            const unsigned short* src =
                vals + (size_t)((sc & 4) ? n1 : n0) * 1024 + vrow * 32 + (sc & 3) * 8;
            async16(src, &Vs[buf][(w * 8) * 64]);
        } else {
            bf16x8 z = (bf16x8){0,0,0,0,0,0,0,0};
            *reinterpret_cast<bf16x8*>(&Vs[buf][vrow * 64 + (l & 7) * 8]) = z;
        }
    };

    auto compute = [&](int buf) {
        #pragma unroll
        for (int kk = 0; kk < 2; ++kk) {
            const int pc = ((kk * 4 + kg) ^ (fr & 7)) * 8;
            bf16x8 af[2], bg[2];
            #pragma unroll
            for (int i = 0; i < 2; ++i)
                af[i] = *reinterpret_cast<const bf16x8*>(
                    &Hs[buf][(wrow + i * 16 + fr) * 64 + pc]);
            #pragma unroll
            for (int jj = 0; jj < 2; ++jj)
                bg[jj] = *reinterpret_cast<const bf16x8*>(
                    &Vs[buf][(jj * 16 + fr) * 64 + pc]);
            #pragma unroll
            for (int i = 0; i < 2; ++i)
                #pragma unroll
                for (int jj = 0; jj < 2; ++jj)
                    acc[i][jj] = __builtin_amdgcn_mfma_f32_16x16x32_bf16(
                        af[i], bg[jj], acc[i][jj], 0, 0, 0);
        }
    };

    __syncthreads();               // colsS visible; pipeline starts clean
    const int nsteps = (cnt + 1) >> 1;   // == 16 here (cnt == 32 uniform)
    stage(0, 0);
    if (nsteps > 1) stage(1, 1);
    int cur = 0;
    for (int js = 0; js < nsteps - 1; ++js) {
        vm_wait<5>();
        barrier();
        compute(cur);
        barrier();
        if (js + 2 < nsteps) stage(cur, js + 2);
        cur ^= 1;
    }
    vm_wait<0>();
    barrier();
    compute(cur);

    const int fq = l >> 4;
    #pragma unroll
    for (int i = 0; i < 2; ++i) {
        const int row0 = bm + wrow + i * 16 + fq * 4;
        #pragma unroll
        for (int jj = 0; jj < 2; ++jj) {
            const int col = r * 32 + jj * 16 + fr;
            const float bv = b2[col];
            #pragma unroll
            for (int v = 0; v < 4; ++v) {
                float rv = fmaxf(acc[i][jj][v] + bv, 0.f);
                h2[(size_t)(row0 + v) * 2048 + col] = f2bf(rv);
            }
        }
    }
}

// ---------------------------------------------------------------------------
extern "C" void kernel_launch(void* const* d_in, const int* in_sizes, int n_in,
                              void* d_out, int out_size, void* d_ws, size_t ws_size,
                              hipStream_t stream) {
    const float* x    = (const float*)d_in[0];   // 2048x1024
    const float* W1   = (const float*)d_in[1];   // 2048x1024
    const float* b1   = (const float*)d_in[2];   // 2048
    const int*   crow = (const int*)d_in[3];     // 65
    const int*   cols = (const int*)d_in[4];     // 2048
    const float* vals = (const float*)d_in[5];   // 2048x32x32
    const float* b2   = (const float*)d_in[6];   // 2048
    const float* W3   = (const float*)d_in[7];   // 1024x2048
    const float* b3   = (const float*)d_in[8];   // 1024
    float* out = (float*)d_out;                  // 2048x1024 f32

    const int NE = 2 * 1024 * 1024;
    unsigned short* xb  = (unsigned short*)d_ws;
    unsigned short* w1b = xb  + NE;
    unsigned short* w3b = w1b + NE;
    unsigned short* vb  = w3b + NE;
    unsigned short* hb  = vb  + NE;              // 4M elems
    unsigned short* h2b = hb  + 2 * NE;          // 4M elems

    cvt4<<<8192, 256, 0, stream>>>(x, W1, W3, vals, xb, w1b, w3b, vb);

    // L1: h = relu(x @ W1^T + b1)  M=2048 N=2048 K=1024, tile 128x64,
    // 16 m-tiles = 8 XCD x 2, 32 n-tiles -> grid 512
    gemm_bt<128, 64, 2, 1, 1><<<512, 256, 0, stream>>>(
        xb, w1b, b1, hb, 2048, 2048, 1024);
    // L2: BSR + relu, grid 1024, bt pinned per XCD
    bsr_layer<<<1024, 256, 0, stream>>>(hb, crow, cols, vb, b2, h2b);
    // L3: out = h2 @ W3^T + b3  M=2048 N=1024 K=2048, tile 64x64,
    // 32 m-tiles = 8 XCD x 4, 16 n-tiles -> grid 512
    gemm_bt<64, 64, 4, 0, 0><<<512, 256, 0, stream>>>(
        h2b, w3b, b3, out, 2048, 1024, 2048);

    (void)in_sizes; (void)n_in; (void)out_size; (void)ws_size;
}